// Round 7
// baseline (56.654 us; speedup 1.0000x reference)
//
#include <hip/hip_runtime.h>
#include <math.h>

#define D 256
#define TWOD 512
#define BB 1024
#define NN 131072
#define LOG2E 1.4426950408889634f

typedef float v4f __attribute__((ext_vector_type(4)));

__device__ __forceinline__ v4f ldg_nt(const float* p, bool valid) {
  v4f z = {0.f, 0.f, 0.f, 0.f};
  if (valid) z = __builtin_nontemporal_load((const v4f*)p);
  return z;
}

__device__ __forceinline__ float dot4(v4f a, v4f b) {
  return fmaf(a.w, b.w, fmaf(a.z, b.z, fmaf(a.y, b.y, a.x * b.x)));
}

// butterfly pack: lane with rot r ends with full sum of row (base + r)
__device__ __forceinline__ float pack4(float d0, float d1, float d2, float d3) {
  float a01 = d0 + __shfl_xor(d1, 4);
  float a23 = d2 + __shfl_xor(d3, 4);
  float s = a01 + __shfl_xor(a23, 8);
  s += __shfl_xor(s, 1);
  s += __shfl_xor(s, 2);
  s += __shfl_xor(s, 16);
  s += __shfl_xor(s, 32);
  return s;
}

// ---------------- t: WvT (blocks 0..15) + WoT (16..47) + offs scatter (48..559)
__global__ __launch_bounds__(256) void t_kernel(
    const float* __restrict__ Wv, const float* __restrict__ Wo,
    const int* __restrict__ bidx,
    float* __restrict__ WvT, float* __restrict__ WoT,
    int* __restrict__ offs) {
  const int blk = blockIdx.x;
  const int t = threadIdx.x;
  if (blk < 48) {
    __shared__ float tile[64][65];
    const float* src; float* dst; int r0, c0, C;
    if (blk < 16) { src = Wv; dst = WvT; C = 256; r0 = (blk >> 2) * 64; c0 = (blk & 3) * 64; }
    else          { int b = blk - 16; src = Wo; dst = WoT; C = 512; r0 = (b >> 3) * 64; c0 = (b & 7) * 64; }
    const int lane = t & 63, sr = t >> 6;
    #pragma unroll 4
    for (int rr = 0; rr < 16; ++rr) {
      const int r = rr * 4 + sr;
      tile[r][lane] = src[(size_t)(r0 + r) * C + c0 + lane];
    }
    __syncthreads();
    #pragma unroll 4
    for (int rr = 0; rr < 16; ++rr) {
      const int r = rr * 4 + sr;
      dst[(size_t)(c0 + r) * 256 + r0 + lane] = tile[lane][r];
    }
  } else {
    const int i = (blk - 48) * 256 + t;
    if (i >= NN) return;
    const int b1 = bidx[i];
    const int b2 = (i + 1 < NN) ? bidx[i + 1] : BB;
    if (i == 0) {
      for (int b = 0; b <= b1; ++b) offs[b] = 0;
    }
    for (int b = b1 + 1; b <= b2; ++b) offs[b] = i + 1;
  }
}

// ---------------- fused: block-local qt + flash + merge + H~ + out, 4 batches/block
__global__ __launch_bounds__(1024) void f_kernel(
    const float* __restrict__ H, const float* __restrict__ V,
    const float* __restrict__ Wq, const float* __restrict__ Wk,
    const float* __restrict__ bq, const int* __restrict__ offs,
    const float* __restrict__ WvT, const float* __restrict__ WoT,
    const float* __restrict__ bv, const float* __restrict__ bo,
    float* __restrict__ out) {
  __shared__ __align__(16) char smem[61440];
  // region A [0,16384): stage-2 partials partq[4][4][256]; later flash ss[16][256]
  // region B [16384,20480): Vs[4][256];             later sN2[256][4]
  // region C [20480,28672): q1s4[256][4] (4 KB) ;   later Us2[512][4] (8 KB)
  // region D [28672,61440): epilogue part[8][4][256]
  float* partq = (float*)smem;                  // [q][i][256]
  float (*ss)[D] = (float(*)[D])smem;           // [16][256]
  float* Vs   = (float*)(smem + 16384);         // [4][256]
  float* sN2  = (float*)(smem + 16384);         // [256][4]
  float* q1s4 = (float*)(smem + 20480);         // [256][4]
  float* Us2  = (float*)(smem + 20480);         // [512][4]
  float (*part)[4][D] = (float(*)[4][D])(smem + 28672);  // [8][4][256]
  __shared__ float sm[16], sd[16];

  const int t = threadIdx.x;
  const int wave = t >> 6, lane = t & 63;
  const int blk = blockIdx.x;
  const int b0 = blk * 4;

  // ---- stage V
  {
    const int i = t >> 8, d = t & 255;
    Vs[i * 256 + d] = V[(size_t)(b0 + i) * D + d];
  }
  __syncthreads();

  // ---- qt stage 1: q1 = Wq V (rotated rows, butterfly), wave covers 16 rows
  {
    const int rot = (lane >> 2) & 3;
    const v4f vb0 = *(const v4f*)&Vs[0 * 256 + lane * 4];
    const v4f vb1 = *(const v4f*)&Vs[1 * 256 + lane * 4];
    const v4f vb2 = *(const v4f*)&Vs[2 * 256 + lane * 4];
    const v4f vb3 = *(const v4f*)&Vs[3 * 256 + lane * 4];
    #pragma unroll
    for (int ii = 0; ii < 4; ++ii) {
      const int cb = wave * 16 + ii * 4;
      const v4f r0 = *(const v4f*)(Wq + (size_t)(cb + (rot ^ 0)) * D + lane * 4);
      const v4f r1 = *(const v4f*)(Wq + (size_t)(cb + (rot ^ 1)) * D + lane * 4);
      const v4f r2 = *(const v4f*)(Wq + (size_t)(cb + (rot ^ 2)) * D + lane * 4);
      const v4f r3 = *(const v4f*)(Wq + (size_t)(cb + (rot ^ 3)) * D + lane * 4);
      const float s0 = pack4(dot4(r0, vb0), dot4(r1, vb0), dot4(r2, vb0), dot4(r3, vb0));
      const float s1 = pack4(dot4(r0, vb1), dot4(r1, vb1), dot4(r2, vb1), dot4(r3, vb1));
      const float s2 = pack4(dot4(r0, vb2), dot4(r1, vb2), dot4(r2, vb2), dot4(r3, vb2));
      const float s3 = pack4(dot4(r0, vb3), dot4(r1, vb3), dot4(r2, vb3), dot4(r3, vb3));
      if (lane < 16 && (lane & 3) == 0) {
        v4f o = {s0, s1, s2, s3};
        *(v4f*)&q1s4[(cb + rot) * 4] = o;
      }
    }
  }
  __syncthreads();

  // ---- qt stage 2: qt = Wk^T (q1 + bq); wave (i = w&3, kq = w>>2) covers k in [kq*64,+64)
  {
    const int i = wave & 3, kq = wave >> 2;
    v4f aq = {0.f, 0.f, 0.f, 0.f};
    const int kb = kq * 64;
    for (int kk = 0; kk < 64; ++kk) {
      const int k = kb + kk;
      const v4f w4 = *(const v4f*)(Wk + (size_t)k * D + lane * 4);
      aq += w4 * (q1s4[k * 4 + i] + bq[k]);
    }
    *(v4f*)&partq[(kq * 4 + i) * 256 + lane * 4] = aq;
  }
  __syncthreads();

  // ---- flash: wave w handles batch ib = w>>2, row-phase qq = w&3 (rows stride 8)
  const int ib = wave >> 2, qq = wave & 3;
  const int bb = b0 + ib;
  const int start = offs[bb], end = offs[bb + 1];

  v4f q4;
  {
    const v4f p0 = *(const v4f*)&partq[(0 * 4 + ib) * 256 + lane * 4];
    const v4f p1 = *(const v4f*)&partq[(1 * 4 + ib) * 256 + lane * 4];
    const v4f p2 = *(const v4f*)&partq[(2 * 4 + ib) * 256 + lane * 4];
    const v4f p3 = *(const v4f*)&partq[(3 * 4 + ib) * 256 + lane * 4];
    q4 = (p0 + p1) + (p2 + p3);
  }
  __syncthreads();   // partq dead; ss region may now be written

  float m = -1e30f, den = 0.f;
  v4f acc = {0.f, 0.f, 0.f, 0.f};
  {
    const float SC = 0.0625f * LOG2E;
    const int odd = lane & 1;
    int n = start + qq * 2;
    v4f c0 = ldg_nt(H + (size_t)n * D + lane * 4, n < end);
    v4f c1 = ldg_nt(H + (size_t)(n + 1) * D + lane * 4, n + 1 < end);
    while (n < end) {
      const int nn = n + 8;
      v4f p0 = ldg_nt(H + (size_t)nn * D + lane * 4, nn < end);
      v4f p1 = ldg_nt(H + (size_t)(nn + 1) * D + lane * 4, nn + 1 < end);

      const float d0 = dot4(c0, q4);
      const float d1 = dot4(c1, q4);
      const float mine = odd ? d1 : d0;
      const float oth  = odd ? d0 : d1;
      float s = mine + __shfl_xor(oth, 1);
      s += __shfl_xor(s, 2);
      s += __shfl_xor(s, 4);
      s += __shfl_xor(s, 8);
      s += __shfl_xor(s, 16);
      s += __shfl_xor(s, 32);
      const float sc = (n + odd < end) ? s * SC : -1e30f;

      const float mm = fmaxf(sc, __shfl_xor(sc, 1));
      const float nm = fmaxf(m, mm);
      const float f = exp2f(m - nm);
      const float w = exp2f(sc - nm);
      const float wx = __shfl_xor(w, 1);
      const float wr0 = odd ? wx : w;
      const float wr1 = odd ? w : wx;
      den = fmaf(den, f, w + wx);
      acc = acc * f + c0 * wr0 + c1 * wr1;
      m = nm;

      c0 = p0; c1 = p1; n = nn;
    }
  }
  *(v4f*)&ss[wave][lane * 4] = acc;
  if (lane == 0) { sm[wave] = m; sd[wave] = den; }
  __syncthreads();

  // ---- merge 4 phase-waves per batch -> sN2; stage V into Us2
  {
    const int i = t >> 8, d = t & 255;
    const int w0 = i * 4;
    const float m0 = sm[w0], m1 = sm[w0 + 1], m2 = sm[w0 + 2], m3 = sm[w0 + 3];
    const float M = fmaxf(fmaxf(m0, m1), fmaxf(m2, m3));
    const float f0 = exp2f(m0 - M), f1 = exp2f(m1 - M);
    const float f2 = exp2f(m2 - M), f3 = exp2f(m3 - M);
    const float Dn = sd[w0] * f0 + sd[w0 + 1] * f1 + sd[w0 + 2] * f2 + sd[w0 + 3] * f3;
    const float inv = (Dn > 0.f) ? (1.f / Dn) : 0.f;
    const float sv = (ss[w0][d] * f0 + ss[w0 + 1][d] * f1 +
                      ss[w0 + 2][d] * f2 + ss[w0 + 3][d] * f3) * inv;
    const float vv = V[(size_t)(b0 + i) * D + d];
    __syncthreads();          // ss read done everywhere before overlay writes
    sN2[d * 4 + i] = sv;
    Us2[d * 4 + i] = vv;
  }
  __syncthreads();

  // ---- phase A: H~ partials, wave covers h in [wave*16,+16)
  v4f a0 = {0.f, 0.f, 0.f, 0.f}, a1 = a0, a2 = a0, a3 = a0;
  {
    const int hb = wave * 16;
    #pragma unroll 4
    for (int hh = 0; hh < 16; ++hh) {
      const int h = hb + hh;
      const v4f w4 = *(const v4f*)(WvT + (size_t)h * D + lane * 4);
      const v4f s4 = *(const v4f*)&sN2[h * 4];     // b128 broadcast
      a0 += w4 * s4.x; a1 += w4 * s4.y; a2 += w4 * s4.z; a3 += w4 * s4.w;
    }
  }
  if (wave >= 8) {
    *(v4f*)&part[wave - 8][0][lane * 4] = a0;
    *(v4f*)&part[wave - 8][1][lane * 4] = a1;
    *(v4f*)&part[wave - 8][2][lane * 4] = a2;
    *(v4f*)&part[wave - 8][3][lane * 4] = a3;
  }
  __syncthreads();
  if (wave < 8) {
    v4f p0 = *(const v4f*)&part[wave][0][lane * 4];
    v4f p1 = *(const v4f*)&part[wave][1][lane * 4];
    v4f p2 = *(const v4f*)&part[wave][2][lane * 4];
    v4f p3 = *(const v4f*)&part[wave][3][lane * 4];
    *(v4f*)&part[wave][0][lane * 4] = a0 + p0;
    *(v4f*)&part[wave][1][lane * 4] = a1 + p1;
    *(v4f*)&part[wave][2][lane * 4] = a2 + p2;
    *(v4f*)&part[wave][3][lane * 4] = a3 + p3;
  }
  __syncthreads();
  {
    const int i = t >> 8, d = t & 255;
    float s = bv[d];
    #pragma unroll
    for (int w = 0; w < 8; ++w) s += part[w][i][d];
    Us2[(D + d) * 4 + i] = s;
  }
  __syncthreads();

  // ---- phase B: out partials, wave covers k in [wave*32,+32)
  a0 = (v4f){0.f, 0.f, 0.f, 0.f}; a1 = a0; a2 = a0; a3 = a0;
  {
    const int kb = wave * 32;
    #pragma unroll 4
    for (int kk = 0; kk < 32; ++kk) {
      const int k = kb + kk;
      const v4f w4 = *(const v4f*)(WoT + (size_t)k * D + lane * 4);
      const v4f u4 = *(const v4f*)&Us2[k * 4];     // b128 broadcast
      a0 += w4 * u4.x; a1 += w4 * u4.y; a2 += w4 * u4.z; a3 += w4 * u4.w;
    }
  }
  if (wave >= 8) {
    *(v4f*)&part[wave - 8][0][lane * 4] = a0;
    *(v4f*)&part[wave - 8][1][lane * 4] = a1;
    *(v4f*)&part[wave - 8][2][lane * 4] = a2;
    *(v4f*)&part[wave - 8][3][lane * 4] = a3;
  }
  __syncthreads();
  if (wave < 8) {
    v4f p0 = *(const v4f*)&part[wave][0][lane * 4];
    v4f p1 = *(const v4f*)&part[wave][1][lane * 4];
    v4f p2 = *(const v4f*)&part[wave][2][lane * 4];
    v4f p3 = *(const v4f*)&part[wave][3][lane * 4];
    *(v4f*)&part[wave][0][lane * 4] = a0 + p0;
    *(v4f*)&part[wave][1][lane * 4] = a1 + p1;
    *(v4f*)&part[wave][2][lane * 4] = a2 + p2;
    *(v4f*)&part[wave][3][lane * 4] = a3 + p3;
  }
  __syncthreads();
  {
    const int i = t >> 8, d = t & 255;
    const int bb2 = b0 + i;
    float s = bo[d];
    #pragma unroll
    for (int w = 0; w < 8; ++w) s += part[w][i][d];
    const int c = offs[bb2 + 1] - offs[bb2];
    out[(size_t)bb2 * D + d] = (c > 0) ? s : Us2[d * 4 + i];
  }
}

extern "C" void kernel_launch(void* const* d_in, const int* in_sizes, int n_in,
                              void* d_out, int out_size, void* d_ws, size_t ws_size,
                              hipStream_t stream) {
  const float* V   = (const float*)d_in[0];
  const float* H   = (const float*)d_in[1];
  const int* bidx  = (const int*)d_in[2];
  const float* Wq  = (const float*)d_in[3];
  const float* bq  = (const float*)d_in[4];
  const float* Wk  = (const float*)d_in[5];
  const float* Wv  = (const float*)d_in[7];
  const float* bv  = (const float*)d_in[8];
  const float* Wo  = (const float*)d_in[9];
  const float* bo  = (const float*)d_in[10];
  float* out = (float*)d_out;

  float* ws  = (float*)d_ws;
  float* WvT = ws;                       // 256*256
  float* WoT = WvT + D * D;              // 512*256
  int* offs  = (int*)(WoT + TWOD * D);   // 1025

  hipLaunchKernelGGL(t_kernel, dim3(560), dim3(256), 0, stream,
                     Wv, Wo, bidx, WvT, WoT, offs);
  hipLaunchKernelGGL(f_kernel, dim3(BB / 4), dim3(1024), 0, stream,
                     H, V, Wq, Wk, bq, offs, WvT, WoT, bv, bo, out);
}

// Round 8
// 46.252 us; speedup vs baseline: 1.2249x; 1.2249x over previous
//
#include <hip/hip_runtime.h>
#include <math.h>

#define D 256
#define TWOD 512
#define BB 1024
#define NN 131072
#define LOG2E 1.4426950408889634f

typedef float v4f __attribute__((ext_vector_type(4)));

__device__ __forceinline__ v4f ldg_nt(const float* p, bool valid) {
  v4f z = {0.f, 0.f, 0.f, 0.f};
  if (valid) z = __builtin_nontemporal_load((const v4f*)p);
  return z;
}

__device__ __forceinline__ float dot4(v4f a, v4f b) {
  return fmaf(a.w, b.w, fmaf(a.z, b.z, fmaf(a.y, b.y, a.x * b.x)));
}

// ---------------- prep:
// blocks 0..63    : Mt[d][k] = sum_e Wq[e][d]*Wk[e][k]        (4 d-rows/block)
// blocks 64..127  : WfT[256+h][d] = P[d][h] = sum_v Wo[d][256+v]*Wv[v][h]  (4 h/block)
// blocks 128..143 : WfT[k][d] = Wo[d][k]  (transpose of Wo_A)
// block 144       : bqt[k] = sum_e Wk[e][k]*bq[e]
// block 145       : c[d] = bo[d] + sum_v Wo[d][256+v]*bv[v]
// blocks 146..657 : offs scatter
__global__ __launch_bounds__(256) void prep_kernel(
    const float* __restrict__ Wq, const float* __restrict__ bq,
    const float* __restrict__ Wk, const float* __restrict__ Wv,
    const float* __restrict__ bv, const float* __restrict__ Wo,
    const float* __restrict__ bo, const int* __restrict__ bidx,
    float* __restrict__ Mt, float* __restrict__ WfT,
    float* __restrict__ bqt, float* __restrict__ cvec,
    int* __restrict__ offs) {
  const int blk = blockIdx.x;
  const int t = threadIdx.x;
  if (blk < 64) {
    const int d0 = blk * 4;
    float a0 = 0.f, a1 = 0.f, a2 = 0.f, a3 = 0.f;
    for (int e = 0; e < D; ++e) {
      const float wk = Wk[(size_t)e * D + t];        // coalesced
      const float* wqr = Wq + (size_t)e * D + d0;    // uniform -> sgpr
      a0 = fmaf(wqr[0], wk, a0);
      a1 = fmaf(wqr[1], wk, a1);
      a2 = fmaf(wqr[2], wk, a2);
      a3 = fmaf(wqr[3], wk, a3);
    }
    Mt[(size_t)(d0 + 0) * D + t] = a0;
    Mt[(size_t)(d0 + 1) * D + t] = a1;
    Mt[(size_t)(d0 + 2) * D + t] = a2;
    Mt[(size_t)(d0 + 3) * D + t] = a3;
  } else if (blk < 128) {
    const int h0 = (blk - 64) * 4;
    float a0 = 0.f, a1 = 0.f, a2 = 0.f, a3 = 0.f;
    for (int v = 0; v < D; ++v) {
      const float wo = Wo[(size_t)t * TWOD + D + v]; // per-lane row walk (L1-window)
      const float* wvr = Wv + (size_t)v * D + h0;    // uniform -> sgpr
      a0 = fmaf(wvr[0], wo, a0);
      a1 = fmaf(wvr[1], wo, a1);
      a2 = fmaf(wvr[2], wo, a2);
      a3 = fmaf(wvr[3], wo, a3);
    }
    WfT[(size_t)(D + h0 + 0) * D + t] = a0;
    WfT[(size_t)(D + h0 + 1) * D + t] = a1;
    WfT[(size_t)(D + h0 + 2) * D + t] = a2;
    WfT[(size_t)(D + h0 + 3) * D + t] = a3;
  } else if (blk < 144) {
    __shared__ float tile[64][65];
    const int b = blk - 128;
    const int r0 = (b >> 2) * 64, c0 = (b & 3) * 64;
    const int lane = t & 63, sr = t >> 6;
    #pragma unroll 4
    for (int rr = 0; rr < 16; ++rr) {
      const int r = rr * 4 + sr;
      tile[r][lane] = Wo[(size_t)(r0 + r) * TWOD + c0 + lane];
    }
    __syncthreads();
    #pragma unroll 4
    for (int rr = 0; rr < 16; ++rr) {
      const int r = rr * 4 + sr;
      WfT[(size_t)(c0 + r) * D + r0 + lane] = tile[lane][r];
    }
  } else if (blk == 144) {
    float a = 0.f;
    for (int e = 0; e < D; ++e)
      a = fmaf(Wk[(size_t)e * D + t], bq[e], a);
    bqt[t] = a;
  } else if (blk == 145) {
    float a = bo[t];
    for (int v = 0; v < D; ++v)
      a = fmaf(Wo[(size_t)t * TWOD + D + v], bv[v], a);
    cvec[t] = a;
  } else {
    const int i = (blk - 146) * 256 + t;
    if (i >= NN) return;
    const int b1 = bidx[i];
    const int b2 = (i + 1 < NN) ? bidx[i + 1] : BB;
    if (i == 0) {
      for (int b = 0; b <= b1; ++b) offs[b] = 0;
    }
    for (int b = b1 + 1; b <= b2; ++b) offs[b] = i + 1;
  }
}

// ---------------- fused: qt-GEMV + flash + merge + single epilogue GEMV, 4 batches/block
__global__ __launch_bounds__(1024) void f_kernel(
    const float* __restrict__ H, const float* __restrict__ V,
    const float* __restrict__ Mt, const float* __restrict__ bqt,
    const int* __restrict__ offs, const float* __restrict__ WfT,
    const float* __restrict__ cvec, float* __restrict__ out) {
  __shared__ __align__(16) char smem[32768 + 4096 + 8192];
  // region A [0,32768): partq[8][4][256] -> flash ss[16][256] -> epi part[8][4][256]
  // region B [32768,36864): Vs[4][256]
  // region C [36864,45056): Us2[512][4]
  float (*partq)[4][D] = (float(*)[4][D])smem;
  float (*ss)[D] = (float(*)[D])smem;
  float (*part)[4][D] = (float(*)[4][D])smem;
  float* Vs  = (float*)(smem + 32768);
  float* Us2 = (float*)(smem + 36864);
  __shared__ float sm[16], sd[16];

  const int t = threadIdx.x;
  const int wave = t >> 6, lane = t & 63;
  const int blk = blockIdx.x;
  const int b0 = blk * 4;

  // ---- stage V
  {
    const int i = t >> 8, d = t & 255;
    Vs[i * 256 + d] = V[(size_t)(b0 + i) * D + d];
  }
  __syncthreads();

  // ---- qt prologue: qt = Mt^T V + bqt ; wave covers d in [wave*16,+16)
  {
    v4f a0 = {0.f, 0.f, 0.f, 0.f}, a1 = a0, a2 = a0, a3 = a0;
    const int db = wave * 16;
    #pragma unroll 4
    for (int dd = 0; dd < 16; ++dd) {
      const int d = db + dd;
      const v4f w4 = *(const v4f*)(Mt + (size_t)d * D + lane * 4);
      a0 += w4 * Vs[0 * 256 + d];
      a1 += w4 * Vs[1 * 256 + d];
      a2 += w4 * Vs[2 * 256 + d];
      a3 += w4 * Vs[3 * 256 + d];
    }
    if (wave >= 8) {
      *(v4f*)&partq[wave - 8][0][lane * 4] = a0;
      *(v4f*)&partq[wave - 8][1][lane * 4] = a1;
      *(v4f*)&partq[wave - 8][2][lane * 4] = a2;
      *(v4f*)&partq[wave - 8][3][lane * 4] = a3;
    }
    __syncthreads();
    if (wave < 8) {
      v4f p0 = *(const v4f*)&partq[wave][0][lane * 4];
      v4f p1 = *(const v4f*)&partq[wave][1][lane * 4];
      v4f p2 = *(const v4f*)&partq[wave][2][lane * 4];
      v4f p3 = *(const v4f*)&partq[wave][3][lane * 4];
      *(v4f*)&partq[wave][0][lane * 4] = a0 + p0;
      *(v4f*)&partq[wave][1][lane * 4] = a1 + p1;
      *(v4f*)&partq[wave][2][lane * 4] = a2 + p2;
      *(v4f*)&partq[wave][3][lane * 4] = a3 + p3;
    }
  }
  __syncthreads();

  // ---- flash: wave w -> batch ib = w>>2, phase qq = w&3 (rows stride 8)
  const int ib = wave >> 2, qq = wave & 3;
  const int bb = b0 + ib;
  const int start = offs[bb], end = offs[bb + 1];

  v4f q4 = *(const v4f*)(bqt + lane * 4);
  #pragma unroll
  for (int w = 0; w < 8; ++w) q4 += *(const v4f*)&partq[w][ib][lane * 4];
  __syncthreads();   // partq dead; ss region may now be written

  float m = -1e30f, den = 0.f;
  v4f acc = {0.f, 0.f, 0.f, 0.f};
  {
    const float SC = 0.0625f * LOG2E;
    const int odd = lane & 1;
    int n = start + qq * 2;
    v4f c0 = ldg_nt(H + (size_t)n * D + lane * 4, n < end);
    v4f c1 = ldg_nt(H + (size_t)(n + 1) * D + lane * 4, n + 1 < end);
    while (n < end) {
      const int nn = n + 8;
      v4f p0 = ldg_nt(H + (size_t)nn * D + lane * 4, nn < end);
      v4f p1 = ldg_nt(H + (size_t)(nn + 1) * D + lane * 4, nn + 1 < end);

      const float d0 = dot4(c0, q4);
      const float d1 = dot4(c1, q4);
      const float mine = odd ? d1 : d0;
      const float oth  = odd ? d0 : d1;
      float s = mine + __shfl_xor(oth, 1);
      s += __shfl_xor(s, 2);
      s += __shfl_xor(s, 4);
      s += __shfl_xor(s, 8);
      s += __shfl_xor(s, 16);
      s += __shfl_xor(s, 32);
      const float sc = (n + odd < end) ? s * SC : -1e30f;

      const float mm = fmaxf(sc, __shfl_xor(sc, 1));
      const float nm = fmaxf(m, mm);
      const float f = exp2f(m - nm);
      const float w = exp2f(sc - nm);
      const float wx = __shfl_xor(w, 1);
      const float wr0 = odd ? wx : w;
      const float wr1 = odd ? w : wx;
      den = fmaf(den, f, w + wx);
      acc = acc * f + c0 * wr0 + c1 * wr1;
      m = nm;

      c0 = p0; c1 = p1; n = nn;
    }
  }
  *(v4f*)&ss[wave][lane * 4] = acc;
  if (lane == 0) { sm[wave] = m; sd[wave] = den; }
  __syncthreads();

  // ---- merge 4 phase-waves per batch -> Us2 = [V ; s_norm]
  {
    const int i = t >> 8, d = t & 255;
    const int w0 = i * 4;
    const float m0 = sm[w0], m1 = sm[w0 + 1], m2 = sm[w0 + 2], m3 = sm[w0 + 3];
    const float M = fmaxf(fmaxf(m0, m1), fmaxf(m2, m3));
    const float f0 = exp2f(m0 - M), f1 = exp2f(m1 - M);
    const float f2 = exp2f(m2 - M), f3 = exp2f(m3 - M);
    const float Dn = sd[w0] * f0 + sd[w0 + 1] * f1 + sd[w0 + 2] * f2 + sd[w0 + 3] * f3;
    const float inv = (Dn > 0.f) ? (1.f / Dn) : 0.f;
    const float sv = (ss[w0][d] * f0 + ss[w0 + 1][d] * f1 +
                      ss[w0 + 2][d] * f2 + ss[w0 + 3][d] * f3) * inv;
    Us2[d * 4 + i] = Vs[i * 256 + d];
    Us2[(D + d) * 4 + i] = sv;
  }
  __syncthreads();

  // ---- epilogue: out = WfT^T Us2 + c ; wave covers k in [wave*32,+32) of K=512
  {
    v4f a0 = {0.f, 0.f, 0.f, 0.f}, a1 = a0, a2 = a0, a3 = a0;
    const int kb = wave * 32;
    #pragma unroll 4
    for (int kk = 0; kk < 32; ++kk) {
      const int k = kb + kk;
      const v4f w4 = *(const v4f*)(WfT + (size_t)k * D + lane * 4);
      const v4f u4 = *(const v4f*)&Us2[k * 4];     // b128 broadcast
      a0 += w4 * u4.x; a1 += w4 * u4.y; a2 += w4 * u4.z; a3 += w4 * u4.w;
    }
    if (wave >= 8) {
      *(v4f*)&part[wave - 8][0][lane * 4] = a0;
      *(v4f*)&part[wave - 8][1][lane * 4] = a1;
      *(v4f*)&part[wave - 8][2][lane * 4] = a2;
      *(v4f*)&part[wave - 8][3][lane * 4] = a3;
    }
    __syncthreads();
    if (wave < 8) {
      v4f p0 = *(const v4f*)&part[wave][0][lane * 4];
      v4f p1 = *(const v4f*)&part[wave][1][lane * 4];
      v4f p2 = *(const v4f*)&part[wave][2][lane * 4];
      v4f p3 = *(const v4f*)&part[wave][3][lane * 4];
      *(v4f*)&part[wave][0][lane * 4] = a0 + p0;
      *(v4f*)&part[wave][1][lane * 4] = a1 + p1;
      *(v4f*)&part[wave][2][lane * 4] = a2 + p2;
      *(v4f*)&part[wave][3][lane * 4] = a3 + p3;
    }
  }
  __syncthreads();
  {
    const int i = t >> 8, d = t & 255;
    const int bb2 = b0 + i;
    float s = cvec[d];
    #pragma unroll
    for (int w = 0; w < 8; ++w) s += part[w][i][d];
    const int c = offs[bb2 + 1] - offs[bb2];
    out[(size_t)bb2 * D + d] = (c > 0) ? s : Us2[d * 4 + i];
  }
}

extern "C" void kernel_launch(void* const* d_in, const int* in_sizes, int n_in,
                              void* d_out, int out_size, void* d_ws, size_t ws_size,
                              hipStream_t stream) {
  const float* V   = (const float*)d_in[0];
  const float* H   = (const float*)d_in[1];
  const int* bidx  = (const int*)d_in[2];
  const float* Wq  = (const float*)d_in[3];
  const float* bq  = (const float*)d_in[4];
  const float* Wk  = (const float*)d_in[5];
  const float* Wv  = (const float*)d_in[7];
  const float* bv  = (const float*)d_in[8];
  const float* Wo  = (const float*)d_in[9];
  const float* bo  = (const float*)d_in[10];
  float* out = (float*)d_out;

  float* ws  = (float*)d_ws;
  float* Mt  = ws;                       // 256*256
  float* WfT = Mt + D * D;               // 512*256
  float* bqt = WfT + TWOD * D;           // 256
  float* cv  = bqt + D;                  // 256
  int* offs  = (int*)(cv + D);           // 1025

  hipLaunchKernelGGL(prep_kernel, dim3(658), dim3(256), 0, stream,
                     Wq, bq, Wk, Wv, bv, Wo, bo, bidx,
                     Mt, WfT, bqt, cv, offs);
  hipLaunchKernelGGL(f_kernel, dim3(BB / 4), dim3(1024), 0, stream,
                     H, V, Mt, bqt, offs, WfT, cv, out);
}